// Round 5
// baseline (1595.441 us; speedup 1.0000x reference)
//
#include <hip/hip_runtime.h>
#include <hip/hip_bf16.h>

// Problem constants (fixed by setup_inputs)
#define TQ   2048
#define TKV  2048
#define NB   2
#define NH   16
#define HD   64
#define CE   1024          // n_embd
#define MQ   (NB*TQ)       // 4096 rows

typedef __bf16 bf16_t;
typedef __bf16 bf16x4_t __attribute__((ext_vector_type(4)));
typedef __bf16 bf16x8_t __attribute__((ext_vector_type(8)));
typedef float  f32x4_t  __attribute__((ext_vector_type(4)));

#define MFMA16(a,b,c) __builtin_amdgcn_mfma_f32_16x16x32_bf16((a),(b),(c),0,0,0)

__device__ __forceinline__ void gload16(const void* g, void* l) {
    __builtin_amdgcn_global_load_lds(
        (__attribute__((address_space(1))) void*)(void*)g,
        (__attribute__((address_space(3))) void*)l, 16, 0, 0);
}

// ---------------- f32 -> (hi,lo) bf16 split, vectorized x4 ----------------
__global__ __launch_bounds__(256) void cvt_split(const float* __restrict__ x,
                                                 bf16_t* __restrict__ hi,
                                                 bf16_t* __restrict__ lo, int n4) {
    int i = blockIdx.x * blockDim.x + threadIdx.x;
    int stride = gridDim.x * blockDim.x;
    for (; i < n4; i += stride) {
        f32x4_t v = ((const f32x4_t*)x)[i];
        bf16x4_t h, l;
#pragma unroll
        for (int j = 0; j < 4; j++) {
            h[j] = (bf16_t)v[j];
            l[j] = (bf16_t)(v[j] - (float)h[j]);
        }
        ((bf16x4_t*)hi)[i] = h;
        ((bf16x4_t*)lo)[i] = l;
    }
}

// ---- weight transpose+split: W f32 [K][N] -> Wh(,Wl) bf16 [N][K] ----
__global__ __launch_bounds__(256) void wsplit_t(const float* __restrict__ W,
                                                bf16_t* __restrict__ Wh,
                                                bf16_t* __restrict__ Wl, int K, int N) {
    __shared__ float t[32][33];
    int tx = threadIdx.x, ty = threadIdx.y;
    int n0 = blockIdx.x * 32, k0 = blockIdx.y * 32;
#pragma unroll
    for (int j = 0; j < 4; j++)
        t[ty + 8*j][tx] = W[(size_t)(k0 + ty + 8*j) * N + n0 + tx];
    __syncthreads();
#pragma unroll
    for (int j = 0; j < 4; j++) {
        float v = t[tx][ty + 8*j];
        bf16_t h = (bf16_t)v;
        Wh[(size_t)(n0 + ty + 8*j) * K + k0 + tx] = h;
        if (Wl)
            Wl[(size_t)(n0 + ty + 8*j) * K + k0 + tx] = (bf16_t)(v - (float)h);
    }
}

// ------- split-precision GEMM body: 128x128 tile, 4 waves, 16x16x32 MFMA -------
// PASSES=3: Ah*Bh + Ah*Bl + Al*Bh. PASSES=2: Ah*Bh + Al*Bh. PASSES=1: Ah*Bh.
template <int PASSES, typename CT>
__device__ __forceinline__ void gemm_body(const bf16_t* __restrict__ Ah,
                                          const bf16_t* __restrict__ Al,
                                          const bf16_t* __restrict__ Bh,
                                          const bf16_t* __restrict__ Bl,
                                          CT* __restrict__ C,
                                          bf16_t* __restrict__ Clo,
                                          int bi, int bj, int N, int K, int Nlo,
                                          bf16_t* As, bf16_t* Bs, int tid) {
    int lane = tid & 63, w = tid >> 6;
    int wr = (w >> 1) * 64, wc = (w & 1) * 64;
    int lr = lane & 15, lg = lane >> 4;
    int row0 = tid >> 2, seg0 = tid & 3;

    f32x4_t acc[4][4];
#pragma unroll
    for (int m = 0; m < 4; m++)
#pragma unroll
        for (int n = 0; n < 4; n++)
            acc[m][n] = f32x4_t{0.f, 0.f, 0.f, 0.f};

    for (int p = 0; p < PASSES; ++p) {
        const bf16_t* Ap;
        const bf16_t* Bp;
        if (p == 0)      { Ap = Ah; Bp = Bh; }
        else if (p == 1) { if (PASSES == 3) { Ap = Ah; Bp = Bl; } else { Ap = Al; Bp = Bh; } }
        else             { Ap = Al; Bp = Bh; }
        for (int k0 = 0; k0 < K; k0 += 32) {
#pragma unroll
            for (int i = 0; i < 2; i++) {
                int row = row0 + i * 64;
                int sseg = seg0 ^ (row & 3);   // pre-swizzled global source, linear LDS dest
                gload16(Ap + (size_t)(bi*128 + row) * K + k0 + sseg*8, (void*)(As + row*32 + seg0*8));
                gload16(Bp + (size_t)(bj*128 + row) * K + k0 + sseg*8, (void*)(Bs + row*32 + seg0*8));
            }
            __syncthreads();
            bf16x8_t af[4], bfr[4];
#pragma unroll
            for (int m = 0; m < 4; m++) {
                int ra = wr + m*16 + lr;
                af[m]  = *(const bf16x8_t*)(As + ra*32 + ((lg ^ (ra & 3)) * 8));
                int rb = wc + m*16 + lr;
                bfr[m] = *(const bf16x8_t*)(Bs + rb*32 + ((lg ^ (rb & 3)) * 8));
            }
#pragma unroll
            for (int m = 0; m < 4; m++)
#pragma unroll
                for (int n = 0; n < 4; n++)
                    acc[m][n] = MFMA16(af[m], bfr[n], acc[m][n]);
            __syncthreads();
        }
    }
#pragma unroll
    for (int m = 0; m < 4; m++) {
        int r = bi*128 + wr + m*16 + lg*4;
#pragma unroll
        for (int n = 0; n < 4; n++) {
            int c = bj*128 + wc + n*16 + lr;
#pragma unroll
            for (int i = 0; i < 4; i++) {
                float v = acc[m][n][i];
                if constexpr (__is_same(CT, float)) {
                    C[(size_t)(r + i) * N + c] = v;
                } else {
                    bf16_t h = (bf16_t)v;
                    C[(size_t)(r + i) * N + c] = h;
                    if (Clo && c < Nlo)
                        Clo[(size_t)(r + i) * Nlo + c] = (bf16_t)(v - (float)h);
                }
            }
        }
    }
}

// ---- v-projection body: single pass, epilogue writes transposed VT layout ----
// A = xkv_hi [4096][1024], B = wkvT_h v-rows [1024][1024], out VT [B*H][64][TKV]
__device__ __forceinline__ void gemm_vt_body(const bf16_t* __restrict__ A,
                                             const bf16_t* __restrict__ B,
                                             bf16_t* __restrict__ VT_,
                                             int bi, int bj,
                                             bf16_t* As, bf16_t* Bs, int tid) {
    const int K = CE;
    int lane = tid & 63, w = tid >> 6;
    int wr = (w >> 1) * 64, wc = (w & 1) * 64;
    int lr = lane & 15, lg = lane >> 4;
    int row0 = tid >> 2, seg0 = tid & 3;

    f32x4_t acc[4][4];
#pragma unroll
    for (int m = 0; m < 4; m++)
#pragma unroll
        for (int n = 0; n < 4; n++)
            acc[m][n] = f32x4_t{0.f, 0.f, 0.f, 0.f};

    for (int k0 = 0; k0 < K; k0 += 32) {
#pragma unroll
        for (int i = 0; i < 2; i++) {
            int row = row0 + i * 64;
            int sseg = seg0 ^ (row & 3);
            gload16(A + (size_t)(bi*128 + row) * K + k0 + sseg*8, (void*)(As + row*32 + seg0*8));
            gload16(B + (size_t)(bj*128 + row) * K + k0 + sseg*8, (void*)(Bs + row*32 + seg0*8));
        }
        __syncthreads();
        bf16x8_t af[4], bfr[4];
#pragma unroll
        for (int m = 0; m < 4; m++) {
            int ra = wr + m*16 + lr;
            af[m]  = *(const bf16x8_t*)(As + ra*32 + ((lg ^ (ra & 3)) * 8));
            int rb = wc + m*16 + lr;
            bfr[m] = *(const bf16x8_t*)(Bs + rb*32 + ((lg ^ (rb & 3)) * 8));
        }
#pragma unroll
        for (int m = 0; m < 4; m++)
#pragma unroll
            for (int n = 0; n < 4; n++)
                acc[m][n] = MFMA16(af[m], bfr[n], acc[m][n]);
        __syncthreads();
    }
    // epilogue: C[r][c] -> VT[(b*16 + c/64)*64 + c%64][t], t = r % 2048, 4 rows contiguous
#pragma unroll
    for (int m = 0; m < 4; m++) {
        int r0 = bi*128 + wr + m*16 + lg*4;
        int bb = r0 >> 11, t = r0 & 2047;
#pragma unroll
        for (int n = 0; n < 4; n++) {
            int c = bj*128 + wc + n*16 + lr;
            int hh = c >> 6, d = c & 63;
            bf16x4_t vv;
#pragma unroll
            for (int i = 0; i < 4; i++) vv[i] = (bf16_t)acc[m][n][i];
            *(bf16x4_t*)(VT_ + ((((size_t)bb*16 + hh)*64 + d)*2048 + t)) = vv;
        }
    }
}

// Fused q/k/v projections: role = id%3 (0=q 3-pass, 1=k 3-pass, 2=v 1-pass+VT)
__global__ __launch_bounds__(256) void gemm_qkv(const bf16_t* xqh, const bf16_t* xql,
                                                const bf16_t* wqh, const bf16_t* wql,
                                                bf16_t* q_hi, bf16_t* q_lo,
                                                const bf16_t* xkh, const bf16_t* xkl,
                                                const bf16_t* wkh, const bf16_t* wkl,
                                                bf16_t* k_hi, bf16_t* k_lo,
                                                bf16_t* vT) {
    __shared__ bf16_t As[128 * 32];
    __shared__ bf16_t Bs[128 * 32];
    int id = blockIdx.x, tid = threadIdx.x;
    int role = id % 3, sub = id / 3;         // sub in [0,256)
    int bi = sub >> 3, bj = sub & 7;
    if (role == 0)
        gemm_body<3, bf16_t>(xqh, xql, wqh, wql, q_hi, q_lo, bi, bj, CE, CE, CE, As, Bs, tid);
    else if (role == 1)
        gemm_body<3, bf16_t>(xkh, xkl, wkh, wkl, k_hi, k_lo, bi, bj, CE, CE, CE, As, Bs, tid);
    else
        gemm_vt_body(xkh, wkh + (size_t)1024*CE, vT, bi, bj, As, Bs, tid);
}

// Out-projection: single pass yh*Wh, f32 output
__global__ __launch_bounds__(256) void gemm_proj(const bf16_t* yh, const bf16_t* wph,
                                                 float* out) {
    __shared__ bf16_t As[128 * 32];
    __shared__ bf16_t Bs[128 * 32];
    int id = blockIdx.x, tid = threadIdx.x;
    gemm_body<1, float>(yh, nullptr, wph, nullptr, out, nullptr,
                        id >> 3, id & 7, CE, CE, 0, As, Bs, tid);
}

// ---------------- fused flash attention v4: pipelined ----------------
// grid: 512 = 16 qt x 32 bh (XCD-swizzled). block: 256 = 4 waves x 32 q-rows.
// K_hi/K_lo double-buffered in LDS (staged one tile ahead); bias prefetched one
// tile ahead into regs; V read direct from global (L2-resident) at tile top.
__global__ __launch_bounds__(256, 2) void attn_fwd4(const bf16_t* __restrict__ Qh,
                                                    const bf16_t* __restrict__ Ql,
                                                    const bf16_t* __restrict__ Khg,
                                                    const bf16_t* __restrict__ Klg,
                                                    const bf16_t* __restrict__ VTg,
                                                    const float*  __restrict__ Bias,
                                                    bf16_t* __restrict__ Yh) {
    __shared__ bf16_t KhS[2][64 * 64];
    __shared__ bf16_t KlS[2][64 * 64];
    __shared__ bf16_t pb[4][32 * 72];    // per-wave P tile: 32 q rows, stride 72

    int id = blockIdx.x;
    int swz = (id & 7) * 64 + (id >> 3);     // XCD-contiguous: 4 heads per XCD
    int qt = swz & 15, bh = swz >> 4;
    int b = bh >> 4, h = bh & 15;
    int tid = threadIdx.x, lane = tid & 63, w = tid >> 6;
    int lr = lane & 15, lg = lane >> 4;
    int q0 = qt * 128 + w * 32;

    // Q fragments (2 q-sets of 16 rows)
    bf16x8_t qhf[2][2], qlf[2][2];
#pragma unroll
    for (int qs = 0; qs < 2; qs++) {
        const bf16_t* qp  = Qh + (size_t)(b*TQ + q0 + qs*16 + lr) * CE + h*HD + lg*8;
        const bf16_t* qp2 = Ql + (size_t)(b*TQ + q0 + qs*16 + lr) * CE + h*HD + lg*8;
        qhf[qs][0] = *(const bf16x8_t*)qp;
        qhf[qs][1] = *(const bf16x8_t*)(qp + 32);
        qlf[qs][0] = *(const bf16x8_t*)qp2;
        qlf[qs][1] = *(const bf16x8_t*)(qp2 + 32);
    }

    float m_r[2][4], l_r[2][4];
    f32x4_t oa[2][4];
#pragma unroll
    for (int qs = 0; qs < 2; qs++)
#pragma unroll
        for (int i = 0; i < 4; i++) {
            m_r[qs][i] = -1e30f; l_r[qs][i] = 0.f;
            oa[qs][i] = f32x4_t{0.f, 0.f, 0.f, 0.f};
        }

    bf16_t* myp = pb[w];
    const float*  bbase = Bias + ((size_t)h*TQ + q0 + lg*4) * TKV + lr;
    const bf16_t* kh0 = Khg + (size_t)b*TKV*CE + h*HD;
    const bf16_t* kl0 = Klg + (size_t)b*TKV*CE + h*HD;
    const bf16_t* vtg = VTg + (size_t)bh * HD * TKV;

    auto STAGE = [&](int bufi, int kv0) {
#pragma unroll
        for (int s = 0; s < 2; s++) {
            int idx = s * 256 + tid;
            int row = idx >> 3;
            int sw  = (idx & 7) ^ (row & 7);
            gload16(kh0 + (size_t)(kv0 + row) * CE + sw*8, (void*)(&KhS[bufi][idx*8]));
            gload16(kl0 + (size_t)(kv0 + row) * CE + sw*8, (void*)(&KlS[bufi][idx*8]));
        }
    };
    auto BLOAD = [&](float (&bv)[2][4][4], int kv0) {
#pragma unroll
        for (int qs = 0; qs < 2; qs++)
#pragma unroll
            for (int i = 0; i < 4; i++)
#pragma unroll
                for (int g = 0; g < 4; g++)
                    bv[qs][g][i] = bbase[(size_t)(qs*16 + i) * TKV + kv0 + g*16];
    };
    auto VLOAD = [&](bf16x8_t (&vf)[4][2], int kv0) {
#pragma unroll
        for (int c = 0; c < 4; c++) {
            const bf16_t* vp = vtg + (size_t)(c*16 + lr) * TKV + kv0 + lg*8;
            vf[c][0] = *(const bf16x8_t*)vp;
            vf[c][1] = *(const bf16x8_t*)(vp + 32);
        }
    };
    auto COMPUTE = [&](int bufi, float (&bv)[2][4][4], bf16x8_t (&vf)[4][2]) {
        // QK^T (3-pass split precision), per-g fragment loads
        f32x4_t sg[2][4];
#pragma unroll
        for (int g = 0; g < 4; g++) {
            int rb = (g*16 + lr) * 64, x = lr & 7;
            bf16x8_t kh_0 = *(const bf16x8_t*)(&KhS[bufi][rb + ((lg     ^ x) * 8)]);
            bf16x8_t kh_1 = *(const bf16x8_t*)(&KhS[bufi][rb + (((4+lg) ^ x) * 8)]);
            bf16x8_t kl_0 = *(const bf16x8_t*)(&KlS[bufi][rb + ((lg     ^ x) * 8)]);
            bf16x8_t kl_1 = *(const bf16x8_t*)(&KlS[bufi][rb + (((4+lg) ^ x) * 8)]);
#pragma unroll
            for (int qs = 0; qs < 2; qs++) {
                f32x4_t s = f32x4_t{0.f, 0.f, 0.f, 0.f};
                s = MFMA16(qhf[qs][0], kh_0, s);
                s = MFMA16(qhf[qs][1], kh_1, s);
                s = MFMA16(qlf[qs][0], kh_0, s);
                s = MFMA16(qlf[qs][1], kh_1, s);
                s = MFMA16(qhf[qs][0], kl_0, s);
                s = MFMA16(qhf[qs][1], kl_1, s);
                sg[qs][g] = s;
            }
        }
        // online softmax
        float p[2][4][4], mx[2][4], mn_[2][4];
        int grow = 0;
#pragma unroll
        for (int qs = 0; qs < 2; qs++)
#pragma unroll
            for (int i = 0; i < 4; i++) {
                float a0 = (sg[qs][0][i] + bv[qs][0][i]) * 8.f;
                float a1 = (sg[qs][1][i] + bv[qs][1][i]) * 8.f;
                float a2 = (sg[qs][2][i] + bv[qs][2][i]) * 8.f;
                float a3 = (sg[qs][3][i] + bv[qs][3][i]) * 8.f;
                p[qs][0][i] = a0; p[qs][1][i] = a1; p[qs][2][i] = a2; p[qs][3][i] = a3;
                mx[qs][i] = fmaxf(fmaxf(a0, a1), fmaxf(a2, a3));
            }
#pragma unroll
        for (int d = 1; d < 16; d <<= 1)
#pragma unroll
            for (int qs = 0; qs < 2; qs++)
#pragma unroll
                for (int i = 0; i < 4; i++)
                    mx[qs][i] = fmaxf(mx[qs][i], __shfl_xor(mx[qs][i], d));
#pragma unroll
        for (int qs = 0; qs < 2; qs++)
#pragma unroll
            for (int i = 0; i < 4; i++) {
                mn_[qs][i] = fmaxf(m_r[qs][i], mx[qs][i]);
                grow |= (mn_[qs][i] > m_r[qs][i]) ? 1 : 0;
            }
        if (__any(grow)) {
#pragma unroll
            for (int qs = 0; qs < 2; qs++)
#pragma unroll
                for (int i = 0; i < 4; i++) {
                    float sc = __expf(m_r[qs][i] - mn_[qs][i]);
                    m_r[qs][i] = mn_[qs][i];
                    l_r[qs][i] *= sc;
#pragma unroll
                    for (int c = 0; c < 4; c++) oa[qs][c][i] *= sc;
                }
        }
        float rs[2][4];
#pragma unroll
        for (int qs = 0; qs < 2; qs++)
#pragma unroll
            for (int i = 0; i < 4; i++) {
                float r = 0.f;
#pragma unroll
                for (int g = 0; g < 4; g++) {
                    p[qs][g][i] = __expf(p[qs][g][i] - m_r[qs][i]);
                    r += p[qs][g][i];
                }
                rs[qs][i] = r;
            }
#pragma unroll
        for (int d = 1; d < 16; d <<= 1)
#pragma unroll
            for (int qs = 0; qs < 2; qs++)
#pragma unroll
                for (int i = 0; i < 4; i++)
                    rs[qs][i] += __shfl_xor(rs[qs][i], d);
#pragma unroll
        for (int qs = 0; qs < 2; qs++)
#pragma unroll
            for (int i = 0; i < 4; i++)
                l_r[qs][i] += rs[qs][i];

        // P -> LDS (wave-private), read back as A-fragments
#pragma unroll
        for (int qs = 0; qs < 2; qs++)
#pragma unroll
            for (int i = 0; i < 4; i++)
#pragma unroll
                for (int g = 0; g < 4; g++)
                    myp[(qs*16 + lg*4 + i)*72 + g*16 + lr] = (bf16_t)p[qs][g][i];
        bf16x8_t pa[2][2];
#pragma unroll
        for (int qs = 0; qs < 2; qs++) {
            pa[qs][0] = *(const bf16x8_t*)(myp + (qs*16 + lr)*72 + lg*8);
            pa[qs][1] = *(const bf16x8_t*)(myp + (qs*16 + lr)*72 + 32 + lg*8);
        }
        // PV from register V fragments
#pragma unroll
        for (int c = 0; c < 4; c++)
#pragma unroll
            for (int qs = 0; qs < 2; qs++) {
                oa[qs][c] = MFMA16(pa[qs][0], vf[c][0], oa[qs][c]);
                oa[qs][c] = MFMA16(pa[qs][1], vf[c][1], oa[qs][c]);
            }
    };

    // ---------------- pipelined main loop ----------------
    float bv_a[2][4][4], bv_b[2][4][4];
    bf16x8_t vfa[4][2], vfb[4][2];

    STAGE(0, 0);
    BLOAD(bv_a, 0);
    __syncthreads();

    for (int it = 0; it < TKV/128; it++) {
        int kvA = it*128, kvB = kvA + 64;
        // tile A (buffer 0)
        VLOAD(vfa, kvA);
        STAGE(1, kvB);
        BLOAD(bv_b, kvB);
        COMPUTE(0, bv_a, vfa);
        __syncthreads();
        // tile B (buffer 1)
        VLOAD(vfb, kvB);
        if (kvB + 64 < TKV) {
            STAGE(0, kvB + 64);
            BLOAD(bv_a, kvB + 64);
        }
        COMPUTE(1, bv_b, vfb);
        __syncthreads();
    }

    // ---- epilogue: Y = O / l ----
#pragma unroll
    for (int qs = 0; qs < 2; qs++)
#pragma unroll
        for (int c = 0; c < 4; c++)
#pragma unroll
            for (int i = 0; i < 4; i++) {
                float yv = oa[qs][c][i] / l_r[qs][i];
                size_t idx = (size_t)(b*TQ + q0 + qs*16 + lg*4 + i) * CE + h*HD + c*16 + lr;
                Yh[idx] = (bf16_t)yv;
            }
}

// ---------------- launch ----------------
extern "C" void kernel_launch(void* const* d_in, const int* in_sizes, int n_in,
                              void* d_out, int out_size, void* d_ws, size_t ws_size,
                              hipStream_t stream) {
    const float* x_q   = (const float*)d_in[0];
    const float* x_kv  = (const float*)d_in[1];
    const float* pbias = (const float*)d_in[2];
    const float* W_q   = (const float*)d_in[3];
    const float* W_kv  = (const float*)d_in[4];
    const float* W_pj  = (const float*)d_in[5];
    float* out = (float*)d_out;

    bf16_t* ws = (bf16_t*)d_ws;
    const size_t MEG = 1024 * 1024;   // bf16-element offsets
    bf16_t* xq_hi  = ws;              //  4M  (reused as y_hi after attn)
    bf16_t* xq_lo  = ws + 4*MEG;      //  4M
    bf16_t* xkv_hi = ws + 8*MEG;      //  4M
    bf16_t* xkv_lo = ws + 12*MEG;     //  4M
    bf16_t* wqT_h  = ws + 16*MEG;     //  1M
    bf16_t* wqT_l  = ws + 17*MEG;     //  1M
    bf16_t* wkvT_h = ws + 18*MEG;     //  2M  (k rows 0..1023, v rows 1024..2047)
    bf16_t* wkvT_l = ws + 20*MEG;     //  2M
    bf16_t* wpT_h  = ws + 22*MEG;     //  1M
    bf16_t* q_hi   = ws + 23*MEG;     //  4M
    bf16_t* q_lo   = ws + 27*MEG;     //  4M
    bf16_t* k_hi   = ws + 31*MEG;     //  4M  [4096][1024]
    bf16_t* k_lo   = ws + 35*MEG;     //  4M
    bf16_t* vT     = ws + 39*MEG;     //  4M  [B*H][64][2048]
    bf16_t* y_hi   = xq_hi;           //  alias (xq dead after gemm_qkv)

    dim3 tb(32, 8);
    cvt_split<<<1024, 256, 0, stream>>>(x_q,  xq_hi,  xq_lo,  (MQ*CE)/4);
    cvt_split<<<1024, 256, 0, stream>>>(x_kv, xkv_hi, xkv_lo, (MQ*CE)/4);
    wsplit_t<<<dim3(32, 32), tb, 0, stream>>>(W_q,  wqT_h,  wqT_l,  CE, CE);
    wsplit_t<<<dim3(64, 32), tb, 0, stream>>>(W_kv, wkvT_h, wkvT_l, CE, 2048);
    wsplit_t<<<dim3(32, 32), tb, 0, stream>>>(W_pj, wpT_h,  nullptr, CE, CE);

    gemm_qkv<<<768, 256, 0, stream>>>(xq_hi, xq_lo, wqT_h, wqT_l, q_hi, q_lo,
                                      xkv_hi, xkv_lo, wkvT_h, wkvT_l, k_hi, k_lo, vT);

    attn_fwd4<<<512, 256, 0, stream>>>(q_hi, q_lo, k_hi, k_lo, vT, pbias, y_hi);

    gemm_proj<<<256, 256, 0, stream>>>(y_hi, wpT_h, out);
}